// Round 18
// baseline (2883.082 us; speedup 1.0000x reference)
//
#include <hip/hip_runtime.h>
#include <stdint.h>

// ---------------------------------------------------------------------------
// BondMatrixMessage: messages[b,e,i] = sum_{k,j} bond[b,e,k] W[k,i,j] src[b,e,j]
// GEMM recast: C[16384 x 64] = A[16384 x 4096] @ W2[4096 x 64]
// R18: REPS=16 DIAGNOSTIC of the R17 fused structure (x3 launches).
// Purpose: decompose R17's 21.5us total into {hot loop/rep, in-kernel fixed,
// inter-launch gap, harness floor} and get MfmaUtil/VALUBusy/FETCH/conflict
// counters for the production structure. bt is read via PLAIN loads (L2-
// cacheable) so reps measure the L2-warm loop rate (unlike R14's gll thrash).
// Kernel math = R17 exactly; rep loop re-zeros acc via runtime-true opq
// (R14-proven, idempotent output). Production = DREPS 1, single launch.
// conn is int32 (harness narrows int64): src idx = conn[e*2].
// ---------------------------------------------------------------------------

#define NATOMS 256
#define DIM 64
#define BT 128   // bonds per block
#define DREPS 16 // diagnostic reps; 1 for production

typedef _Float16 f16;
typedef _Float16 f16x2 __attribute__((ext_vector_type(2)));
typedef _Float16 f16x8 __attribute__((ext_vector_type(8)));
typedef float f32x16 __attribute__((ext_vector_type(16)));

union H8 { f16x8 v8; f16x2 v2[4]; };
union F8 { float4 v4[2]; float f[8]; };

static __device__ __forceinline__ unsigned swz16(unsigned lane) {
    return (lane * 16u) ^ ((lane & 0x38u) << 1);
}

__global__ __launch_bounds__(512, 1) void bond_msg(
    const float* __restrict__ atom, const float* __restrict__ bond,
    const int* __restrict__ conn, const float* __restrict__ bt,
    float* __restrict__ out)
{
    // LDS: stage ring buf[pb(2)][kh(2)][q(4)][s(4)][64 x 16B] = 64 KB (f16).
    //      epilogue reuses [0,16K) for kh-pair reduce.
    __shared__ __align__(16) unsigned char smem[65536];

    const int tid  = threadIdx.x;
    const int lane = tid & 63;
    const int w    = tid >> 6;     // wave 0..7
    const int mt   = w & 3;        // m-tile (32 bonds each)
    const int kh   = w >> 2;       // k half (k in [kh*32, kh*32+32))
    const int lo   = lane & 31;
    const int hi   = lane >> 5;
    const int blk  = blockIdx.x;
    const int btile = blk >> 1;    // bond tile 0..127
    const int ch   = blk & 1;      // column half (32 cols)
    const int bond0 = btile * BT;  // 4 tiles per batch; never straddles

    // ---- staging addresses (coalesced): lane l, wave mt reads 8 consecutive
    // f32 of each kg row-half at mt*512 + l*8 (lane stride 32B).
    const float* gsrc = bt + (size_t)ch * 2048 + (size_t)mt * 512
                      + (size_t)lane * 8;
    // fragment slot this lane produces (per q): s=(l&7)>>1, slot, XOR ^(s<<5)
    const int u_     = lane & 7;
    const int s_     = u_ >> 1;
    const int iloc_  = mt * 8 + (lane >> 3);
    const int slot_  = (u_ & 1) * 32 + iloc_;
    const unsigned woff = (unsigned)((s_ * 1024 + slot_ * 16) ^ (s_ << 5));
    char* lwq = reinterpret_cast<char*>(smem) + kh * 16384 + woff;
    unsigned roff[4];
    #pragma unroll
    for (int s = 0; s < 4; ++s)
        roff[s] = (unsigned)((s * 1024 + lane * 16) ^ (s << 5));
    const char* lrq = reinterpret_cast<const char*>(smem) + kh * 16384;

    // ---- this wave's bond row e and its 32 k-values (dup'd f16 pairs)
    const int e = bond0 + mt * 32 + lo;
    const int ia = conn[e * 2];
    f16x2 bp[32];
    {
        const float* brow = bond + (size_t)e * DIM + kh * 32;
        #pragma unroll
        for (int q = 0; q < 8; ++q) {
            const float4 v = *reinterpret_cast<const float4*>(brow + q * 4);
            const f16 a0 = (f16)v.x, a1 = (f16)v.y, a2 = (f16)v.z, a3 = (f16)v.w;
            bp[q*4+0] = (f16x2){a0,a0}; bp[q*4+1] = (f16x2){a1,a1};
            bp[q*4+2] = (f16x2){a2,a2}; bp[q*4+3] = (f16x2){a3,a3};
        }
    }

    // ---- src atom row -> registers (f16 pairs); j = s*16 + hi*8 + {0..7}
    const float* arow = atom + (size_t)(btile >> 2) * (NATOMS * DIM)
                      + (size_t)ia * DIM;
    f16x2 srcv[4][4];
    #pragma unroll
    for (int s = 0; s < 4; ++s) {
        const int j0 = s * 16 + hi * 8;
        const float4 p0 = *reinterpret_cast<const float4*>(arow + j0);
        const float4 p1 = *reinterpret_cast<const float4*>(arow + j0 + 4);
        srcv[s][0] = (f16x2){ (f16)p0.x, (f16)p0.y };
        srcv[s][1] = (f16x2){ (f16)p0.z, (f16)p0.w };
        srcv[s][2] = (f16x2){ (f16)p1.x, (f16)p1.y };
        srcv[s][3] = (f16x2){ (f16)p1.z, (f16)p1.w };
    }

    // ---- T14 staging: coalesced f32 loads (early) ... cvt+ds_write (late)
    F8 sA[4], sB[4];   // 4 kg-rows x 8 f32

    #define LOADR(S, p) do { if ((p) < 8) {                               \
        _Pragma("unroll")                                                 \
        for (int q = 0; q < 4; ++q) {                                     \
            const float* _g = gsrc                                        \
                + (size_t)(kh * 32 + (p) * 4 + q) * 4096;                 \
            S[q].v4[0] = *reinterpret_cast<const float4*>(_g);            \
            S[q].v4[1] = *reinterpret_cast<const float4*>(_g + 4);        \
        }                                                                 \
    } } while (0)

    #define WRITE(S, p) do { if ((p) < 8) {                               \
        char* _l = lwq + ((p) & 1) * 32768;                               \
        _Pragma("unroll")                                                 \
        for (int q = 0; q < 4; ++q) {                                     \
            const f16x8 h = { (f16)S[q].f[0], (f16)S[q].f[1],             \
                              (f16)S[q].f[2], (f16)S[q].f[3],             \
                              (f16)S[q].f[4], (f16)S[q].f[5],             \
                              (f16)S[q].f[6], (f16)S[q].f[7] };           \
            *reinterpret_cast<f16x8*>(_l + q * 4096) = h;                 \
        }                                                                 \
    } } while (0)

    #define LDSBAR() do {                                                 \
        asm volatile("s_waitcnt lgkmcnt(0)" ::: "memory");                \
        __builtin_amdgcn_s_barrier();                                     \
        __builtin_amdgcn_sched_barrier(0);                                \
    } while (0)

    f32x16 acc = {};
    const bool opq = (ia > -2000000000);   // runtime-true; defeats rep DCE/LICM

    #define COMPUTE(p) do {                                               \
        const char* _rb = lrq + ((p) & 1) * 32768;                        \
        _Pragma("unroll")                                                 \
        for (int q = 0; q < 4; ++q) {                                     \
            const f16x2 _c = bp[(p) * 4 + q];                             \
            _Pragma("unroll")                                             \
            for (int s = 0; s < 4; ++s) {                                 \
                const f16x8 bf = *reinterpret_cast<const f16x8*>(         \
                    _rb + q * 4096 + roff[s]);                            \
                H8 _a;                                                    \
                _Pragma("unroll")                                         \
                for (int t = 0; t < 4; ++t) _a.v2[t] = _c * srcv[s][t];   \
                acc = __builtin_amdgcn_mfma_f32_32x32x16_f16(_a.v8, bf, acc, 0, 0, 0); \
            }                                                             \
        }                                                                 \
    } while (0)

    // STEP(p,S): issue loads for p+1 (early), compute p, cvt+write p+1 (late)
    #define STEP(p, S) do {                                               \
        LOADR(S, (p) + 1);                                                \
        __builtin_amdgcn_sched_barrier(0);                                \
        COMPUTE(p);                                                       \
        __builtin_amdgcn_sched_barrier(0);                                \
        WRITE(S, (p) + 1);  /* compiler inserts vmcnt wait before cvt */  \
        LDSBAR();                                                         \
    } while (0)

    #pragma unroll 1
    for (int rep = 0; rep < DREPS; ++rep) {
        if (opq) acc = (f32x16){};
        // prologue: phase 0 staged via sA (parity-0 buffers; safe across the
        // rep boundary: all parity-0 reads finished before STEP(6)'s barrier)
        LOADR(sA, 0);
        WRITE(sA, 0);
        LDSBAR();
        STEP(0, sB); STEP(1, sA); STEP(2, sB); STEP(3, sA);
        STEP(4, sB); STEP(5, sA); STEP(6, sB);
        COMPUTE(7);
    }

    #undef STEP
    #undef COMPUTE
    #undef LDSBAR
    #undef WRITE
    #undef LOADR

    // ---- epilogue: kh-pair reduce through LDS [0,16K), kh=0 writes C
    __syncthreads();
    if (kh == 1) {
        const unsigned so = swz16((unsigned)lane);
        #pragma unroll
        for (int g = 0; g < 4; ++g) {
            float4 v = { acc[4*g+0], acc[4*g+1], acc[4*g+2], acc[4*g+3] };
            *reinterpret_cast<float4*>(smem + mt*4096 + g*1024 + so) = v;
        }
    }
    __syncthreads();
    if (kh == 0) {
        const unsigned so = swz16((unsigned)lane);
        #pragma unroll
        for (int g = 0; g < 4; ++g) {
            const float4 v = *reinterpret_cast<const float4*>(
                smem + mt*4096 + g*1024 + so);
            acc[4*g+0] += v.x; acc[4*g+1] += v.y;
            acc[4*g+2] += v.z; acc[4*g+3] += v.w;
        }
        const int colb = ch * 32 + lo;
        #pragma unroll
        for (int r = 0; r < 16; ++r) {
            // C/D map: col = lane&31, row = (r&3) + 8*(r>>2) + 4*(lane>>5)
            const int rl = (r & 3) + 8 * (r >> 2) + 4 * hi;
            out[(size_t)(bond0 + mt * 32 + rl) * 64 + colb] = acc[r];
        }
    }
}

extern "C" void kernel_launch(void* const* d_in, const int* in_sizes, int n_in,
                              void* d_out, int out_size, void* d_ws, size_t ws_size,
                              hipStream_t stream) {
    const float* atom = (const float*)d_in[0];   // (32,256,64) f32
    const float* bond = (const float*)d_in[1];   // (32,512,64) f32
    const int*   conn = (const int*)d_in[2];     // (32,512,2) int32 (narrowed)
    const float* bt   = (const float*)d_in[3];   // (64,4096) f32
    float* out = (float*)d_out;                  // (32,512,64) f32

    // R18: three instrumented launches (idempotent output). Per-dispatch
    // dur -> hot loop/rep; timestamps -> inter-launch gap; counters ->
    // MfmaUtil/VALUBusy/FETCH/conflicts for the production structure.
    bond_msg<<<256, 512, 0, stream>>>(atom, bond, conn, bt, out);
    bond_msg<<<256, 512, 0, stream>>>(atom, bond, conn, bt, out);
    bond_msg<<<256, 512, 0, stream>>>(atom, bond, conn, bt, out);
}

// Round 19
// 21.459 us; speedup vs baseline: 134.3509x; 134.3509x over previous
//
#include <hip/hip_runtime.h>
#include <stdint.h>

// ---------------------------------------------------------------------------
// BondMatrixMessage: messages[b,e,i] = sum_{k,j} bond[b,e,k] W[k,i,j] src[b,e,j]
// GEMM recast: C[16384 x 64] = A[16384 x 4096] @ W2[4096 x 64]
//   A[e, k*64+j] = bond[e,k]*src[e,j]  (registers, v_pk_mul_f16)
// R19: R17 fused kernel + two fixes from R18's counters:
//  (1) ds_write bank-conflict fix: R18 showed 8.4M SQ_LDS_BANK_CONFLICT.
//      Old XOR gave write bank-groups (l>>3)^(l&6) -> lanes 0/1,2/3,...
//      alias 2-way. New XOR adds ^((slot&32)>>1) (bit9->bit4): groups
//      (l>>3)^(l&6)^(l&1) = permutation per 8-lane cluster -> conflict-free.
//      Same XOR applied on the read side (rule #21); reads stay a contiguous
//      permutation (conflict-free).
//  (2) Parallel epilogue: all 8 waves store acc to LDS (32KB, contiguous =
//      conflict-free), ONE barrier, all 512 threads reduce kh-pairs and
//      write float4-coalesced C (was: 4 waves idle + 128B scalar stores).
// Geometry: 256 blocks = 128 bond-tiles (BT=128) x 2 col-halves; 8 waves =
// 4 m-tiles x 2 k-halves; 8 phases; T14 issue-early/write-late staging of
// raw f32 bt (L2-cacheable plain loads; R14 proved gll bypasses L2 reuse).
// conn is int32 (harness narrows int64): src idx = conn[e*2].
// ---------------------------------------------------------------------------

#define NATOMS 256
#define DIM 64
#define BT 128   // bonds per block

typedef _Float16 f16;
typedef _Float16 f16x2 __attribute__((ext_vector_type(2)));
typedef _Float16 f16x8 __attribute__((ext_vector_type(8)));
typedef float f32x16 __attribute__((ext_vector_type(16)));

union H8 { f16x8 v8; f16x2 v2[4]; };
union F8 { float4 v4[2]; float f[8]; };

__global__ __launch_bounds__(512, 1) void bond_msg(
    const float* __restrict__ atom, const float* __restrict__ bond,
    const int* __restrict__ conn, const float* __restrict__ bt,
    float* __restrict__ out)
{
    // LDS: stage ring buf[pb(2)][kh(2)][q(4)][4KB frag buffer] = 64 KB (f16).
    //      epilogue reuses [0,32K) for the all-wave acc dump.
    __shared__ __align__(16) unsigned char smem[65536];

    const int tid  = threadIdx.x;
    const int lane = tid & 63;
    const int w    = tid >> 6;     // wave 0..7
    const int mt   = w & 3;        // m-tile (32 bonds each)
    const int kh   = w >> 2;       // k half (k in [kh*32, kh*32+32))
    const int lo   = lane & 31;
    const int hi   = lane >> 5;
    const int blk  = blockIdx.x;
    const int btile = blk >> 1;    // bond tile 0..127
    const int ch   = blk & 1;      // column half (32 cols)
    const int bond0 = btile * BT;  // 4 tiles per batch; never straddles

    // ---- staging addresses (coalesced): lane l, wave mt reads 8 consecutive
    // f32 of each kg row-half at mt*512 + l*8 (lane stride 32B).
    const float* gsrc = bt + (size_t)ch * 2048 + (size_t)mt * 512
                      + (size_t)lane * 8;
    // fragment slot this lane produces (per q): s=(l&7)>>1,
    // slot=(l&1)*32 + mt*8 + (l>>3); XOR ^(s<<5) ^ ((slot&32)>>1)
    const int u_     = lane & 7;
    const int s_     = u_ >> 1;
    const int iloc_  = mt * 8 + (lane >> 3);
    const int slot_  = (u_ & 1) * 32 + iloc_;
    const unsigned woff = (unsigned)((s_ * 1024 + slot_ * 16)
                                     ^ (s_ << 5) ^ ((slot_ & 32) >> 1));
    char* lwq = reinterpret_cast<char*>(smem) + kh * 16384 + woff;
    unsigned roff[4];
    #pragma unroll
    for (int s = 0; s < 4; ++s)
        roff[s] = (unsigned)((s * 1024 + lane * 16)
                             ^ (s << 5) ^ ((lane & 32) >> 1));
    const char* lrq = reinterpret_cast<const char*>(smem) + kh * 16384;

    // ---- this wave's bond row e and its 32 k-values (dup'd f16 pairs)
    const int e = bond0 + mt * 32 + lo;
    const int ia = conn[e * 2];
    f16x2 bp[32];
    {
        const float* brow = bond + (size_t)e * DIM + kh * 32;
        #pragma unroll
        for (int q = 0; q < 8; ++q) {
            const float4 v = *reinterpret_cast<const float4*>(brow + q * 4);
            const f16 a0 = (f16)v.x, a1 = (f16)v.y, a2 = (f16)v.z, a3 = (f16)v.w;
            bp[q*4+0] = (f16x2){a0,a0}; bp[q*4+1] = (f16x2){a1,a1};
            bp[q*4+2] = (f16x2){a2,a2}; bp[q*4+3] = (f16x2){a3,a3};
        }
    }

    // ---- src atom row -> registers (f16 pairs); j = s*16 + hi*8 + {0..7}
    const float* arow = atom + (size_t)(btile >> 2) * (NATOMS * DIM)
                      + (size_t)ia * DIM;
    f16x2 srcv[4][4];
    #pragma unroll
    for (int s = 0; s < 4; ++s) {
        const int j0 = s * 16 + hi * 8;
        const float4 p0 = *reinterpret_cast<const float4*>(arow + j0);
        const float4 p1 = *reinterpret_cast<const float4*>(arow + j0 + 4);
        srcv[s][0] = (f16x2){ (f16)p0.x, (f16)p0.y };
        srcv[s][1] = (f16x2){ (f16)p0.z, (f16)p0.w };
        srcv[s][2] = (f16x2){ (f16)p1.x, (f16)p1.y };
        srcv[s][3] = (f16x2){ (f16)p1.z, (f16)p1.w };
    }

    // ---- T14 staging: coalesced f32 loads (early) ... cvt+ds_write (late)
    F8 sA[4], sB[4];   // 4 kg-rows x 8 f32

    #define LOADR(S, p) do { if ((p) < 8) {                               \
        _Pragma("unroll")                                                 \
        for (int q = 0; q < 4; ++q) {                                     \
            const float* _g = gsrc                                        \
                + (size_t)(kh * 32 + (p) * 4 + q) * 4096;                 \
            S[q].v4[0] = *reinterpret_cast<const float4*>(_g);            \
            S[q].v4[1] = *reinterpret_cast<const float4*>(_g + 4);        \
        }                                                                 \
    } } while (0)

    #define WRITE(S, p) do { if ((p) < 8) {                               \
        char* _l = lwq + ((p) & 1) * 32768;                               \
        _Pragma("unroll")                                                 \
        for (int q = 0; q < 4; ++q) {                                     \
            const f16x8 h = { (f16)S[q].f[0], (f16)S[q].f[1],             \
                              (f16)S[q].f[2], (f16)S[q].f[3],             \
                              (f16)S[q].f[4], (f16)S[q].f[5],             \
                              (f16)S[q].f[6], (f16)S[q].f[7] };           \
            *reinterpret_cast<f16x8*>(_l + q * 4096) = h;                 \
        }                                                                 \
    } } while (0)

    #define LDSBAR() do {                                                 \
        asm volatile("s_waitcnt lgkmcnt(0)" ::: "memory");                \
        __builtin_amdgcn_s_barrier();                                     \
        __builtin_amdgcn_sched_barrier(0);                                \
    } while (0)

    f32x16 acc = {};

    #define COMPUTE(p) do {                                               \
        const char* _rb = lrq + ((p) & 1) * 32768;                        \
        _Pragma("unroll")                                                 \
        for (int q = 0; q < 4; ++q) {                                     \
            const f16x2 _c = bp[(p) * 4 + q];                             \
            _Pragma("unroll")                                             \
            for (int s = 0; s < 4; ++s) {                                 \
                const f16x8 bf = *reinterpret_cast<const f16x8*>(         \
                    _rb + q * 4096 + roff[s]);                            \
                H8 _a;                                                    \
                _Pragma("unroll")                                         \
                for (int t = 0; t < 4; ++t) _a.v2[t] = _c * srcv[s][t];   \
                acc = __builtin_amdgcn_mfma_f32_32x32x16_f16(_a.v8, bf, acc, 0, 0, 0); \
            }                                                             \
        }                                                                 \
    } while (0)

    // STEP(p,S): issue loads for p+1 (early), compute p, cvt+write p+1 (late)
    #define STEP(p, S) do {                                               \
        LOADR(S, (p) + 1);                                                \
        __builtin_amdgcn_sched_barrier(0);                                \
        COMPUTE(p);                                                       \
        __builtin_amdgcn_sched_barrier(0);                                \
        WRITE(S, (p) + 1);  /* compiler inserts vmcnt wait before cvt */  \
        LDSBAR();                                                         \
    } while (0)

    // prologue: phase 0 staged via sA
    LOADR(sA, 0);
    WRITE(sA, 0);
    LDSBAR();

    STEP(0, sB); STEP(1, sA); STEP(2, sB); STEP(3, sA);
    STEP(4, sB); STEP(5, sA); STEP(6, sB);
    COMPUTE(7);

    #undef STEP
    #undef COMPUTE
    #undef LDSBAR
    #undef WRITE
    #undef LOADR

    // ---- epilogue v2: all waves dump acc (32KB, contiguous stores =
    // conflict-free), one barrier, 512 threads reduce kh-pairs + write
    // float4-coalesced C.
    // storage float4: (kh*16 + mt*4 + g)*1024 + lane*16
    //   holds C row mt*32 + 8g + 4*(lane>>5) + j, col = lane&31 (j=0..3)
    __syncthreads();
    {
        #pragma unroll
        for (int g = 0; g < 4; ++g) {
            float4 v = { acc[4*g+0], acc[4*g+1], acc[4*g+2], acc[4*g+3] };
            *reinterpret_cast<float4*>(
                smem + (((w << 2) + g) << 10) + lane * 16) = v;
        }
    }
    __syncthreads();
    {
        const float* smf = reinterpret_cast<const float*>(smem);
        #pragma unroll
        for (int sw = 0; sw < 2; ++sw) {
            const int r   = (tid >> 3) + 64 * sw;   // 0..127
            const int cl0 = (tid & 7) * 4;          // 0,4,..,28
            const int mt_ = r >> 5;
            const int rr  = r & 31;
            const int g_  = rr >> 3;
            const int hi_ = (rr >> 2) & 1;
            const int j_  = rr & 3;
            const int base0 = ((mt_ * 4 + g_) << 8) + hi_ * 128 + j_;
            float4 v;
            #pragma unroll
            for (int c = 0; c < 4; ++c) {
                const int off = base0 + (cl0 + c) * 4;
                v[c] = smf[off] + smf[off + 4096];   // kh=0 + kh=1
            }
            *reinterpret_cast<float4*>(
                out + (size_t)(bond0 + r) * 64 + ch * 32 + cl0) = v;
        }
    }
}

extern "C" void kernel_launch(void* const* d_in, const int* in_sizes, int n_in,
                              void* d_out, int out_size, void* d_ws, size_t ws_size,
                              hipStream_t stream) {
    const float* atom = (const float*)d_in[0];   // (32,256,64) f32
    const float* bond = (const float*)d_in[1];   // (32,512,64) f32
    const int*   conn = (const int*)d_in[2];     // (32,512,2) int32 (narrowed)
    const float* bt   = (const float*)d_in[3];   // (64,4096) f32
    float* out = (float*)d_out;                  // (32,512,64) f32

    bond_msg<<<256, 512, 0, stream>>>(atom, bond, conn, bt, out);
}